// Round 1
// baseline (1508.342 us; speedup 1.0000x reference)
//
#include <hip/hip_runtime.h>
#include <hip/hip_bf16.h>

#define DD 128
#define DEG 32

// ---------------------------------------------------------------------------
// Kernel 1: P[u] = u2e[u] @ W1[0:128,:]          (neighbor half)
//           Q[u] = u2e[u] @ W1[128:256,:] + b1   (center half, b1 folded)
// block = 256 threads, 16 users per block.
// thread t: r = t&15 (row), cg = t>>4 (16 col-groups of 16 cols over P||Q).
// ---------------------------------------------------------------------------
__global__ __launch_bounds__(256) void k_pq(
    const float* __restrict__ u2e, const float* __restrict__ W1,
    const float* __restrict__ b1, float* __restrict__ P,
    float* __restrict__ Q, int U)
{
    __shared__ float su[16][132];   // pad 132: 2-way read aliasing (free)
    const int t = threadIdx.x;
    const int base = blockIdx.x * 16;

    // stage 16 rows (512 float4), coalesced
    #pragma unroll
    for (int i = 0; i < 2; ++i) {
        int idx4 = i * 256 + t;        // 0..511
        int r  = idx4 >> 5;            // 32 float4 per row
        int kc = idx4 & 31;
        int row = base + r;
        float4 v = make_float4(0.f, 0.f, 0.f, 0.f);
        if (row < U) v = *reinterpret_cast<const float4*>(&u2e[(size_t)row * DD + kc * 4]);
        *reinterpret_cast<float4*>(&su[r][kc * 4]) = v;
    }
    __syncthreads();

    const int r    = t & 15;
    const int cg   = t >> 4;            // 0..15
    const int half = cg >> 3;           // 0 -> P, 1 -> Q
    const int colb = (cg & 7) * 16;     // 0..112
    const float* wbase = W1 + (size_t)(half * DD) * DD + colb;

    float acc[16];
    #pragma unroll
    for (int c = 0; c < 16; ++c) acc[c] = 0.f;

    #pragma unroll 4
    for (int k = 0; k < DD; ++k) {
        float u = su[r][k];                                   // LDS, 2-way max
        const float4* w4 = reinterpret_cast<const float4*>(wbase + (size_t)k * DD);
        #pragma unroll
        for (int c4 = 0; c4 < 4; ++c4) {
            float4 w = w4[c4];
            acc[c4 * 4 + 0] = fmaf(u, w.x, acc[c4 * 4 + 0]);
            acc[c4 * 4 + 1] = fmaf(u, w.y, acc[c4 * 4 + 1]);
            acc[c4 * 4 + 2] = fmaf(u, w.z, acc[c4 * 4 + 2]);
            acc[c4 * 4 + 3] = fmaf(u, w.w, acc[c4 * 4 + 3]);
        }
    }

    const int row = base + r;
    if (row < U) {
        if (half == 0) {
            float* dst = P + (size_t)row * DD + colb;
            #pragma unroll
            for (int c4 = 0; c4 < 4; ++c4)
                *reinterpret_cast<float4*>(dst + c4 * 4) =
                    make_float4(acc[c4*4+0], acc[c4*4+1], acc[c4*4+2], acc[c4*4+3]);
        } else {
            float* dst = Q + (size_t)row * DD + colb;
            #pragma unroll
            for (int c4 = 0; c4 < 4; ++c4)
                *reinterpret_cast<float4*>(dst + c4 * 4) =
                    make_float4(acc[c4*4+0] + b1[colb + c4*4 + 0],
                                acc[c4*4+1] + b1[colb + c4*4 + 1],
                                acc[c4*4+2] + b1[colb + c4*4 + 2],
                                acc[c4*4+3] + b1[colb + c4*4 + 3]);
        }
    }
}

// ---------------------------------------------------------------------------
// Kernel 2: one block per node (256 threads).
//   h1[j][k] = relu(P[nb_j][k] + Q[u][k])            (b1 folded in Q)
//   h2 = relu(h1 @ W2 + b2);  s_j = h2 . w3          (b3 cancels in softmax)
//   att = softmax_32(s);  out[node] = sum_j att_j * u2e[nb_j]
// ---------------------------------------------------------------------------
__global__ __launch_bounds__(256) void k_node(
    const int* __restrict__ nodes, const int* __restrict__ neigh,
    const float* __restrict__ u2e, const float* __restrict__ P,
    const float* __restrict__ Q, const float* __restrict__ W2,
    const float* __restrict__ b2, const float* __restrict__ w3,
    float* __restrict__ out)
{
    __shared__ float s_h1[DEG][133];   // pad 133: (5j+k)%32 conflict-free reads
    __shared__ float s_qu[DD];
    __shared__ int   s_nb[DEG];
    __shared__ float s_ps[256];
    __shared__ float s_s[DEG];
    __shared__ float s_att[DEG];
    __shared__ float s_o[2][DD];

    const int t = threadIdx.x;
    const int node = blockIdx.x;
    const int u = nodes[node];                    // uniform -> scalar load

    if (t < DEG) s_nb[t] = neigh[node * DEG + t];
    if (t < DD)  s_qu[t] = Q[(size_t)u * DD + t];
    __syncthreads();

    // ---- h1 into LDS: 4096 elems as 1024 float4 gathers (coalesced rows)
    #pragma unroll
    for (int i = 0; i < 4; ++i) {
        int idx4 = i * 256 + t;        // 0..1023
        int j  = idx4 >> 5;            // 32 float4 per row
        int k4 = idx4 & 31;
        int nb = s_nb[j];
        float4 p = *reinterpret_cast<const float4*>(&P[(size_t)nb * DD + k4 * 4]);
        float4 q = *reinterpret_cast<const float4*>(&s_qu[k4 * 4]);
        s_h1[j][k4 * 4 + 0] = fmaxf(p.x + q.x, 0.f);
        s_h1[j][k4 * 4 + 1] = fmaxf(p.y + q.y, 0.f);
        s_h1[j][k4 * 4 + 2] = fmaxf(p.z + q.z, 0.f);
        s_h1[j][k4 * 4 + 3] = fmaxf(p.w + q.w, 0.f);
    }
    __syncthreads();

    // ---- second layer GEMM: thread (j = t&31, cg = t>>5) -> 16 cols
    const int j    = t & 31;
    const int cg   = t >> 5;
    const int colb = cg * 16;
    float acc[16];
    #pragma unroll
    for (int c = 0; c < 16; ++c) acc[c] = 0.f;

    #pragma unroll 2
    for (int k = 0; k < DD; ++k) {
        float h = s_h1[j][k];                                  // conflict-free
        const float4* w4 = reinterpret_cast<const float4*>(&W2[(size_t)k * DD + colb]);
        #pragma unroll
        for (int c4 = 0; c4 < 4; ++c4) {
            float4 w = w4[c4];
            acc[c4 * 4 + 0] = fmaf(h, w.x, acc[c4 * 4 + 0]);
            acc[c4 * 4 + 1] = fmaf(h, w.y, acc[c4 * 4 + 1]);
            acc[c4 * 4 + 2] = fmaf(h, w.z, acc[c4 * 4 + 2]);
            acc[c4 * 4 + 3] = fmaf(h, w.w, acc[c4 * 4 + 3]);
        }
    }

    // relu + dot with w3 -> partial logit for edge j
    float ps = 0.f;
    #pragma unroll
    for (int c = 0; c < 16; ++c) {
        float v = fmaxf(acc[c] + b2[colb + c], 0.f);
        ps = fmaf(v, w3[colb + c], ps);
    }
    s_ps[t] = ps;
    __syncthreads();

    // deterministic reduction over the 8 col-groups
    if (t < DEG) {
        float s = 0.f;
        #pragma unroll
        for (int g = 0; g < 8; ++g) s += s_ps[g * 32 + t];
        s_s[t] = s;
    }
    __syncthreads();

    // ---- softmax over 32 neighbors (lanes 0..31 of wave 0)
    if (t < DEG) {
        float sj = s_s[t];
        float m = sj;
        #pragma unroll
        for (int mask = 16; mask > 0; mask >>= 1)
            m = fmaxf(m, __shfl_xor(m, mask, 64));
        float e = __expf(sj - m);
        float sum = e;
        #pragma unroll
        for (int mask = 16; mask > 0; mask >>= 1)
            sum += __shfl_xor(sum, mask, 64);
        s_att[t] = e / sum;
    }
    __syncthreads();

    // ---- out[node][col] = sum_j att_j * u2e[nb_j][col]   (exact fp32)
    const int col = t & 127;
    const int jh  = t >> 7;
    float o = 0.f;
    #pragma unroll
    for (int jj = 0; jj < 16; ++jj) {
        int jn = jh * 16 + jj;
        o = fmaf(s_att[jn], u2e[(size_t)s_nb[jn] * DD + col], o);
    }
    s_o[jh][col] = o;
    __syncthreads();
    if (t < DD) out[(size_t)node * DD + t] = s_o[0][t] + s_o[1][t];
}

// ---------------------------------------------------------------------------
extern "C" void kernel_launch(void* const* d_in, const int* in_sizes, int n_in,
                              void* d_out, int out_size, void* d_ws, size_t ws_size,
                              hipStream_t stream)
{
    const int*   nodes = (const int*)  d_in[0];
    const int*   neigh = (const int*)  d_in[1];
    // d_in[2] seg_ids: implicitly repeat(arange(n), DEG) -> not needed
    const float* u2e   = (const float*)d_in[3];
    const float* W1    = (const float*)d_in[4];
    const float* b1    = (const float*)d_in[5];
    const float* W2    = (const float*)d_in[6];
    const float* b2    = (const float*)d_in[7];
    const float* w3    = (const float*)d_in[8];
    // d_in[9] b3: scalar shift, cancels in segment softmax

    const int n = in_sizes[0];            // 20000 nodes
    const int U = in_sizes[3] / DD;       // 100000 users

    float* P = (float*)d_ws;              // [U][128]
    float* Q = P + (size_t)U * DD;        // [U][128]  (needs ~102.4 MB of ws)

    const int blocks1 = (U + 15) / 16;
    k_pq<<<blocks1, 256, 0, stream>>>(u2e, W1, b1, P, Q, U);
    k_node<<<n, 256, 0, stream>>>(nodes, neigh, u2e, P, Q, W2, b2, w3, (float*)d_out);
}

// Round 2
// 168.712 us; speedup vs baseline: 8.9403x; 8.9403x over previous
//
#include <hip/hip_runtime.h>
#include <hip/hip_bf16.h>

#define DD 128
#define DEG 32

typedef __attribute__((ext_vector_type(8))) short short8;
typedef __attribute__((ext_vector_type(4))) float f32x4;

__device__ __forceinline__ ushort f2bs(float x) {
    __hip_bfloat16 h = __float2bfloat16(x);     // RNE
    return *reinterpret_cast<ushort*>(&h);
}
__device__ __forceinline__ float bs2f(ushort u) {
    return __uint_as_float(((unsigned)u) << 16);   // exact widening
}
__device__ __forceinline__ unsigned pack2(float a, float b) {
    return (unsigned)f2bs(a) | ((unsigned)f2bs(b) << 16);
}

// ---------------------------------------------------------------------------
// Prep: build bf16, transposed, XOR-swizzled LDS images of [W1a|W1b] and W2.
// Image layout (B-operand): logical wt[n][k] bf16 at byte (n*256+2k)^((n&7)<<4).
// ---------------------------------------------------------------------------
__global__ __launch_bounds__(256) void k_prep(
    const float* __restrict__ W1, const float* __restrict__ W2,
    unsigned* __restrict__ w1img, unsigned* __restrict__ w2img)
{
    int t = blockIdx.x * 256 + threadIdx.x;
    if (t < 256 * 64) {                       // W1 image: n in [0,256), kk in [0,64)
        int n = t >> 6, kk = t & 63, k = kk * 2;
        float v0, v1;
        if (n < DD) { v0 = W1[k * DD + n];        v1 = W1[(k + 1) * DD + n]; }
        else        { v0 = W1[(DD + k) * DD + n - DD]; v1 = W1[(DD + k + 1) * DD + n - DD]; }
        int byte = (n * 256 + kk * 4) ^ ((n & 7) << 4);
        w1img[byte >> 2] = pack2(v0, v1);
    } else if (t < 256 * 64 + 128 * 64) {     // W2 image
        int q = t - 256 * 64;
        int n = q >> 6, kk = q & 63, k = kk * 2;
        float v0 = W2[k * DD + n], v1 = W2[(k + 1) * DD + n];
        int byte = (n * 256 + kk * 4) ^ ((n & 7) << 4);
        w2img[byte >> 2] = pack2(v0, v1);
    }
}

// ---------------------------------------------------------------------------
// k_pq: [P|Q](u) = u2e[u] @ [W1a|W1b] (+b1 on Q half), bf16 out via MFMA.
// Block: 64 users (M=64), N=256, K=128. Wave w owns M-tile w (16 rows).
// ---------------------------------------------------------------------------
__global__ __launch_bounds__(256) void k_pq(
    const float* __restrict__ u2e, const float* __restrict__ b1,
    const float4* __restrict__ w1img4, ushort* __restrict__ Pb,
    ushort* __restrict__ Qb, int U)
{
    __shared__ __align__(16) char a_lds[64 * 256];    // 16 KB bf16 swizzled
    __shared__ __align__(16) char b_lds[256 * 256];   // 64 KB image
    const int t = threadIdx.x;
    const int w = t >> 6, l = t & 63;
    const int base = blockIdx.x * 64;

    // stage A: rows base..base+63 of u2e -> bf16 swizzled
    #pragma unroll
    for (int i = 0; i < 4; ++i) {
        int flat = i * 256 + t;               // (row, c8) over 64x16
        int row = flat >> 4, c8 = flat & 15;
        int grow = base + row;
        float4 v0 = make_float4(0, 0, 0, 0), v1 = v0;
        if (grow < U) {
            v0 = *reinterpret_cast<const float4*>(&u2e[grow * DD + c8 * 8]);
            v1 = *reinterpret_cast<const float4*>(&u2e[grow * DD + c8 * 8 + 4]);
        }
        uint4 r;
        r.x = pack2(v0.x, v0.y); r.y = pack2(v0.z, v0.w);
        r.z = pack2(v1.x, v1.y); r.w = pack2(v1.z, v1.w);
        int off = (row * 256 + c8 * 16) ^ ((row & 7) << 4);
        *reinterpret_cast<uint4*>(a_lds + off) = r;
    }
    {   // stage B image (linear copy, already swizzled)
        float4* bd = reinterpret_cast<float4*>(b_lds);
        #pragma unroll
        for (int i = 0; i < 16; ++i) bd[i * 256 + t] = w1img4[i * 256 + t];
    }
    __syncthreads();

    short8 a[4];
    {
        int row = w * 16 + (l & 15);
        int sw = (row & 7) << 4;
        #pragma unroll
        for (int k4 = 0; k4 < 4; ++k4)
            a[k4] = *reinterpret_cast<const short8*>(
                a_lds + ((row * 256 + k4 * 64 + (l >> 4) * 16) ^ sw));
    }
    const int rbase = base + w * 16 + (l >> 4) * 4;
    #pragma unroll
    for (int nt = 0; nt < 16; ++nt) {
        int col = nt * 16 + (l & 15);
        int sw = (col & 7) << 4;
        short8 b[4];
        #pragma unroll
        for (int k4 = 0; k4 < 4; ++k4)
            b[k4] = *reinterpret_cast<const short8*>(
                b_lds + ((col * 256 + k4 * 64 + (l >> 4) * 16) ^ sw));
        f32x4 acc = {0.f, 0.f, 0.f, 0.f};
        #pragma unroll
        for (int k4 = 0; k4 < 4; ++k4)
            acc = __builtin_amdgcn_mfma_f32_16x16x32_bf16(a[k4], b[k4], acc, 0, 0, 0);
        if (nt < 8) {                          // P half
            #pragma unroll
            for (int r = 0; r < 4; ++r)
                if (rbase + r < U) Pb[(rbase + r) * DD + col] = f2bs(acc[r]);
        } else {                               // Q half, fold b1
            float bb = b1[col - DD];
            #pragma unroll
            for (int r = 0; r < 4; ++r)
                if (rbase + r < U) Qb[(rbase + r) * DD + (col - DD)] = f2bs(acc[r] + bb);
        }
    }
}

// ---------------------------------------------------------------------------
// k_node: 4 nodes/block. h1 = relu(P[nb]+Q[u]) -> bf16 LDS (swizzled);
// h2 GEMM via MFMA (M=128,N=128,K=128); logits -> wave softmax ->
// exact fp32 attention-weighted sum of u2e.
// ---------------------------------------------------------------------------
__global__ __launch_bounds__(256) void k_node(
    const int* __restrict__ nodes, const int* __restrict__ neigh,
    const float* __restrict__ u2e, const ushort* __restrict__ Pb,
    const ushort* __restrict__ Qb, const float4* __restrict__ w2img4,
    const float* __restrict__ b2, const float* __restrict__ w3,
    float* __restrict__ out, int n)
{
    __shared__ __align__(16) char h_lds[128 * 256];   // 32 KB h1 bf16 swizzled
    __shared__ __align__(16) char w_lds[128 * 256];   // 32 KB W2 image
    __shared__ float s_qf[4 * DD];
    __shared__ int   s_nb[128];
    __shared__ int   s_u[4];
    __shared__ float s_lp[4][128];
    __shared__ float s_att[128];

    const int t = threadIdx.x;
    const int w = t >> 6, l = t & 63;
    const int base = blockIdx.x * 4;

    if (t < 4)   s_u[t] = nodes[min(base + t, n - 1)];
    if (t < 128) s_nb[t] = neigh[min(base * DEG + t, n * DEG - 1)];
    __syncthreads();
    #pragma unroll
    for (int i = 0; i < 2; ++i) {             // Q rows of the 4 centers -> fp32 LDS
        int flat = i * 256 + t;
        int g = flat >> 7, k = flat & 127;
        s_qf[flat] = bs2f(Qb[s_u[g] * DD + k]);
    }
    {   // stage W2 image (linear copy)
        float4* wd = reinterpret_cast<float4*>(w_lds);
        #pragma unroll
        for (int i = 0; i < 8; ++i) wd[i * 256 + t] = w2img4[i * 256 + t];
    }
    __syncthreads();

    // h1 build: gather P rows (bf16), add Q, relu, store swizzled bf16
    #pragma unroll
    for (int i = 0; i < 8; ++i) {
        int flat = i * 256 + t;               // (row, c8) over 128x16
        int row = flat >> 4, c8 = flat & 15;
        int nb = s_nb[row];
        const float* q = &s_qf[(row >> 5) * DD + c8 * 8];
        uint4 pv = *reinterpret_cast<const uint4*>(&Pb[nb * DD + c8 * 8]);
        uint4 r;
        r.x = pack2(fmaxf(bs2f((ushort)(pv.x & 0xffff)) + q[0], 0.f),
                    fmaxf(bs2f((ushort)(pv.x >> 16))    + q[1], 0.f));
        r.y = pack2(fmaxf(bs2f((ushort)(pv.y & 0xffff)) + q[2], 0.f),
                    fmaxf(bs2f((ushort)(pv.y >> 16))    + q[3], 0.f));
        r.z = pack2(fmaxf(bs2f((ushort)(pv.z & 0xffff)) + q[4], 0.f),
                    fmaxf(bs2f((ushort)(pv.z >> 16))    + q[5], 0.f));
        r.w = pack2(fmaxf(bs2f((ushort)(pv.w & 0xffff)) + q[6], 0.f),
                    fmaxf(bs2f((ushort)(pv.w >> 16))    + q[7], 0.f));
        int off = (row * 256 + c8 * 16) ^ ((row & 7) << 4);
        *reinterpret_cast<uint4*>(h_lds + off) = r;
    }
    __syncthreads();

    // GEMM: wave w owns cols [32w, 32w+32)
    short8 bf[2][4]; float b2v[2], w3v[2];
    #pragma unroll
    for (int nh = 0; nh < 2; ++nh) {
        int col = w * 32 + nh * 16 + (l & 15);
        b2v[nh] = b2[col]; w3v[nh] = w3[col];
        int sw = (col & 7) << 4;
        #pragma unroll
        for (int k4 = 0; k4 < 4; ++k4)
            bf[nh][k4] = *reinterpret_cast<const short8*>(
                w_lds + ((col * 256 + k4 * 64 + (l >> 4) * 16) ^ sw));
    }
    #pragma unroll
    for (int m = 0; m < 8; ++m) {
        int row = m * 16 + (l & 15);
        int sw = (row & 7) << 4;
        short8 a[4];
        #pragma unroll
        for (int k4 = 0; k4 < 4; ++k4)
            a[k4] = *reinterpret_cast<const short8*>(
                h_lds + ((row * 256 + k4 * 64 + (l >> 4) * 16) ^ sw));
        float pl[4] = {0.f, 0.f, 0.f, 0.f};
        #pragma unroll
        for (int nh = 0; nh < 2; ++nh) {
            f32x4 acc = {0.f, 0.f, 0.f, 0.f};
            #pragma unroll
            for (int k4 = 0; k4 < 4; ++k4)
                acc = __builtin_amdgcn_mfma_f32_16x16x32_bf16(a[k4], bf[nh][k4], acc, 0, 0, 0);
            #pragma unroll
            for (int r = 0; r < 4; ++r)
                pl[r] += fmaxf(acc[r] + b2v[nh], 0.f) * w3v[nh];   // h2 . w3 partial
        }
        #pragma unroll
        for (int mask = 1; mask <= 8; mask <<= 1) {
            #pragma unroll
            for (int r = 0; r < 4; ++r) pl[r] += __shfl_xor(pl[r], mask);
        }
        if ((l & 15) == 0) {
            #pragma unroll
            for (int r = 0; r < 4; ++r) s_lp[w][m * 16 + (l >> 4) * 4 + r] = pl[r];
        }
    }
    __syncthreads();

    // segment softmax over each node's 32 edges (32-lane groups)
    if (t < 128) {
        float sj = s_lp[0][t] + s_lp[1][t] + s_lp[2][t] + s_lp[3][t];
        float mx = sj;
        #pragma unroll
        for (int mask = 16; mask > 0; mask >>= 1) mx = fmaxf(mx, __shfl_xor(mx, mask));
        float e = __expf(sj - mx);
        float sm = e;
        #pragma unroll
        for (int mask = 16; mask > 0; mask >>= 1) sm += __shfl_xor(sm, mask);
        s_att[t] = e / sm;
    }
    __syncthreads();

    // out[node] = sum_j att_j * u2e[nb_j]  (exact fp32)
    #pragma unroll
    for (int h = 0; h < 2; ++h) {
        int item = h * 256 + t;
        int g = item >> 7, c = item & 127;
        int jb = g * DEG;
        float o = 0.f;
        #pragma unroll 8
        for (int j = 0; j < DEG; ++j)
            o = fmaf(s_att[jb + j], u2e[s_nb[jb + j] * DD + c], o);
        if (base + g < n) out[(base + g) * DD + c] = o;
    }
}

// ---------------------------------------------------------------------------
extern "C" void kernel_launch(void* const* d_in, const int* in_sizes, int n_in,
                              void* d_out, int out_size, void* d_ws, size_t ws_size,
                              hipStream_t stream)
{
    const int*   nodes = (const int*)  d_in[0];
    const int*   neigh = (const int*)  d_in[1];
    const float* u2e   = (const float*)d_in[3];
    const float* W1    = (const float*)d_in[4];
    const float* b1    = (const float*)d_in[5];
    const float* W2    = (const float*)d_in[6];
    const float* b2    = (const float*)d_in[7];
    const float* w3    = (const float*)d_in[8];
    // d_in[9] b3: cancels in segment softmax

    const int n = in_sizes[0];            // 20000
    const int U = in_sizes[3] / DD;       // 100000

    unsigned* w1img = (unsigned*)d_ws;            // 64 KB
    unsigned* w2img = w1img + 256 * 64;           // 32 KB
    ushort*   Pb    = (ushort*)(w2img + 128 * 64);// 25.6 MB
    ushort*   Qb    = Pb + (size_t)U * DD;        // 25.6 MB

    k_prep<<<96, 256, 0, stream>>>(W1, W2, w1img, w2img);
    k_pq<<<(U + 63) / 64, 256, 0, stream>>>(u2e, b1, (const float4*)w1img, Pb, Qb, U);
    k_node<<<(n + 3) / 4, 256, 0, stream>>>(nodes, neigh, u2e, Pb, Qb,
                                            (const float4*)w2img, b2, w3,
                                            (float*)d_out, n);
}

// Round 4
// 132.571 us; speedup vs baseline: 11.3776x; 1.2726x over previous
//
#include <hip/hip_runtime.h>
#include <hip/hip_bf16.h>

#define DD 128
#define DEG 32

typedef __attribute__((ext_vector_type(8))) short short8;
typedef __attribute__((ext_vector_type(4))) float f32x4;

__device__ __forceinline__ ushort f2bs(float x) {
    __hip_bfloat16 h = __float2bfloat16(x);     // RNE
    return *reinterpret_cast<ushort*>(&h);
}
__device__ __forceinline__ float bs2f(ushort u) {
    return __uint_as_float(((unsigned)u) << 16);   // exact widening
}
__device__ __forceinline__ unsigned pack2(float a, float b) {
    return (unsigned)f2bs(a) | ((unsigned)f2bs(b) << 16);
}
// relu(bf16(p_lo)+bf16(q_lo)), relu(bf16(p_hi)+bf16(q_hi)) -> packed bf16 pair
__device__ __forceinline__ unsigned relu_add_pack(unsigned p, unsigned q) {
    float a0 = __uint_as_float(p << 16)        + __uint_as_float(q << 16);
    float a1 = __uint_as_float(p & 0xffff0000u) + __uint_as_float(q & 0xffff0000u);
    return pack2(fmaxf(a0, 0.f), fmaxf(a1, 0.f));
}

// ---------------------------------------------------------------------------
// k_prep: build MFMA fragment images in ws (read straight from global later).
//  w1img (B-op, 64KB): frag(nt,k4,l)[i] = B1[k4*32+(l>>4)*8+i][nt*16+(l&15)]
//     where B1[k][n] = W1[k][n] (n<128)  |  W1[128+k][n-128] (n>=128)
//  w2t  (A-op, 32KB): frag(mt,k4,l)[i] = W2[k4*32+(l>>4)*8+i][mt*16+(l&15)]
// ---------------------------------------------------------------------------
__global__ __launch_bounds__(256) void k_prep(
    const float* __restrict__ W1, const float* __restrict__ W2,
    uint4* __restrict__ w1img, uint4* __restrict__ w2t)
{
    int t = blockIdx.x * 256 + threadIdx.x;
    if (t < 4096) {                     // w1: idx = (nt*4+k4)*64 + l
        int l = t & 63, f = t >> 6, k4 = f & 3, nt = f >> 2;
        int n = nt * 16 + (l & 15), kb = k4 * 32 + ((l >> 4) & 3) * 8;
        float v[8];
        #pragma unroll
        for (int i = 0; i < 8; ++i) {
            int k = kb + i;
            v[i] = (n < DD) ? W1[k * DD + n] : W1[(DD + k) * DD + (n - DD)];
        }
        uint4 r;
        r.x = pack2(v[0], v[1]); r.y = pack2(v[2], v[3]);
        r.z = pack2(v[4], v[5]); r.w = pack2(v[6], v[7]);
        w1img[t] = r;
    } else if (t < 6144) {              // w2t: idx = (mt*4+k4)*64 + l
        int q = t - 4096;
        int l = q & 63, f = q >> 6, k4 = f & 3, mt = f >> 2;
        int ch = mt * 16 + (l & 15), kb = k4 * 32 + ((l >> 4) & 3) * 8;
        float v[8];
        #pragma unroll
        for (int i = 0; i < 8; ++i) v[i] = W2[(kb + i) * DD + ch];
        uint4 r;
        r.x = pack2(v[0], v[1]); r.y = pack2(v[2], v[3]);
        r.z = pack2(v[4], v[5]); r.w = pack2(v[6], v[7]);
        w2t[q] = r;
    }
}

// ---------------------------------------------------------------------------
// k_pq: [P|Q](u) = u2e[u] @ [W1a|W1b] (+b1 on Q), bf16 out. 128 users/block.
// Wave w owns rows [32w,32w+32); B fragments read from global w1img (L1-hot).
// ---------------------------------------------------------------------------
__global__ __launch_bounds__(256) void k_pq(
    const float* __restrict__ u2e, const float* __restrict__ b1,
    const short8* __restrict__ w1img, ushort* __restrict__ Pb,
    ushort* __restrict__ Qb, int U)
{
    __shared__ __align__(16) char a_lds[128 * 256];   // 32 KB bf16 swizzled
    const int t = threadIdx.x;
    const int w = t >> 6, l = t & 63;
    const int base = blockIdx.x * 128;

    #pragma unroll
    for (int i = 0; i < 8; ++i) {
        int flat = i * 256 + t;               // (row, c8) over 128x16
        int row = flat >> 4, c8 = flat & 15;
        int grow = base + row;
        float4 v0 = make_float4(0, 0, 0, 0), v1 = v0;
        if (grow < U) {
            v0 = *reinterpret_cast<const float4*>(&u2e[(size_t)grow * DD + c8 * 8]);
            v1 = *reinterpret_cast<const float4*>(&u2e[(size_t)grow * DD + c8 * 8 + 4]);
        }
        uint4 r;
        r.x = pack2(v0.x, v0.y); r.y = pack2(v0.z, v0.w);
        r.z = pack2(v1.x, v1.y); r.w = pack2(v1.z, v1.w);
        int off = (row * 256 + c8 * 16) ^ ((row & 7) << 4);
        *reinterpret_cast<uint4*>(a_lds + off) = r;
    }
    __syncthreads();

    short8 a[2][4];
    #pragma unroll
    for (int mt = 0; mt < 2; ++mt) {
        int row = w * 32 + mt * 16 + (l & 15);
        int sw = (row & 7) << 4;
        #pragma unroll
        for (int k4 = 0; k4 < 4; ++k4)
            a[mt][k4] = *reinterpret_cast<const short8*>(
                a_lds + ((row * 256 + k4 * 64 + (l >> 4) * 16) ^ sw));
    }

    #pragma unroll 4
    for (int nt = 0; nt < 16; ++nt) {
        short8 b[4];
        #pragma unroll
        for (int k4 = 0; k4 < 4; ++k4) b[k4] = w1img[(nt * 4 + k4) * 64 + l];
        int col = nt * 16 + (l & 15);
        #pragma unroll
        for (int mt = 0; mt < 2; ++mt) {
            f32x4 acc = {0.f, 0.f, 0.f, 0.f};
            #pragma unroll
            for (int k4 = 0; k4 < 4; ++k4)
                acc = __builtin_amdgcn_mfma_f32_16x16x32_bf16(a[mt][k4], b[k4], acc, 0, 0, 0);
            int rb = base + w * 32 + mt * 16 + (l >> 4) * 4;
            if (col < DD) {
                #pragma unroll
                for (int r = 0; r < 4; ++r)
                    if (rb + r < U) Pb[(size_t)(rb + r) * DD + col] = f2bs(acc[r]);
            } else {
                float bb = b1[col - DD];
                #pragma unroll
                for (int r = 0; r < 4; ++r)
                    if (rb + r < U) Qb[(size_t)(rb + r) * DD + (col - DD)] = f2bs(acc[r] + bb);
            }
        }
    }
}

// ---------------------------------------------------------------------------
// k_node: 4 nodes/block (1 node per wave).
//  h1 = relu(P[nb]+Q[u]) -> bf16 swizzled LDS.
//  Swapped GEMM: D[ch][edge] = mfma(A=W2^T frag (global), B=h1 frag (LDS)).
//  Logit = in-lane relu-dot + 2 shuffles; in-wave softmax; prefetched
//  float4 u2e gather (16 rows/thread) -> exact fp32 weighted sum.
// ---------------------------------------------------------------------------
__global__ __launch_bounds__(256) void k_node(
    const int* __restrict__ nodes, const int* __restrict__ neigh,
    const float4* __restrict__ u2e4, const uint4* __restrict__ Pb4,
    const uint4* __restrict__ Qb4, const short8* __restrict__ w2t,
    const float* __restrict__ b2, const float* __restrict__ w3,
    float4* __restrict__ out4, int n)
{
    __shared__ __align__(16) char h_lds[128 * 256];   // 32 KB; aliased post-GEMM
    __shared__ uint4 s_q16[4][16];                    // Q rows, packed bf16
    __shared__ int   s_nb[128];
    __shared__ int   s_u[4];
    __shared__ float s_att[128];
    float4* s_part = reinterpret_cast<float4*>(h_lds);  // [2][128] float4

    const int t = threadIdx.x;
    const int w = t >> 6, l = t & 63;
    const int base = blockIdx.x * 4;

    if (t < 4)   s_u[t] = nodes[min(base + t, n - 1)];
    if (t < 128) s_nb[t] = neigh[min(base * DEG + t, n * DEG - 1)];
    __syncthreads();
    if (t < 64)  s_q16[t >> 4][t & 15] = Qb4[(size_t)s_u[t >> 4] * 16 + (t & 15)];
    __syncthreads();

    // ---- h1 build: gather Pb rows, add Q, relu, store swizzled bf16
    #pragma unroll
    for (int i = 0; i < 8; ++i) {
        int flat = i * 256 + t;               // (row, c8) over 128x16
        int row = flat >> 4, c8 = flat & 15;
        int nb = s_nb[row];
        uint4 pv = Pb4[(size_t)nb * 16 + c8];
        uint4 qv = s_q16[row >> 5][c8];
        uint4 r;
        r.x = relu_add_pack(pv.x, qv.x);
        r.y = relu_add_pack(pv.y, qv.y);
        r.z = relu_add_pack(pv.z, qv.z);
        r.w = relu_add_pack(pv.w, qv.w);
        int off = (row * 256 + c8 * 16) ^ ((row & 7) << 4);
        *reinterpret_cast<uint4*>(h_lds + off) = r;
    }

    // ---- prefetch final-gather u2e rows into registers (hides under GEMM)
    // 256 threads = 2 edge-halves (jg) x 128 (node g, col4) units;
    // each thread covers 16 of the node's 32 edges.
    const int unit = t & 127, jg = t >> 7;
    const int g = unit >> 5, c4 = unit & 31;
    float4 pre[16];
    #pragma unroll
    for (int j = 0; j < 16; ++j)
        pre[j] = u2e4[(size_t)s_nb[g * DEG + jg * 16 + j] * 32 + c4];
    __syncthreads();

    // ---- swapped GEMM + logit fold
    short8 hb[2][4];
    #pragma unroll
    for (int nt = 0; nt < 2; ++nt) {
        int erow = w * 32 + nt * 16 + (l & 15);
        int sw = (erow & 7) << 4;
        #pragma unroll
        for (int k4 = 0; k4 < 4; ++k4)
            hb[nt][k4] = *reinterpret_cast<const short8*>(
                h_lds + ((erow * 256 + k4 * 64 + (l >> 4) * 16) ^ sw));
    }
    float pl0 = 0.f, pl1 = 0.f;
    #pragma unroll
    for (int mt = 0; mt < 8; ++mt) {
        short8 wf[4];
        #pragma unroll
        for (int k4 = 0; k4 < 4; ++k4) wf[k4] = w2t[(mt * 4 + k4) * 64 + l];
        float4 b2v = *reinterpret_cast<const float4*>(&b2[mt * 16 + (l >> 4) * 4]);
        float4 w3v = *reinterpret_cast<const float4*>(&w3[mt * 16 + (l >> 4) * 4]);
        f32x4 a0 = {0.f, 0.f, 0.f, 0.f}, a1 = {0.f, 0.f, 0.f, 0.f};
        #pragma unroll
        for (int k4 = 0; k4 < 4; ++k4)
            a0 = __builtin_amdgcn_mfma_f32_16x16x32_bf16(wf[k4], hb[0][k4], a0, 0, 0, 0);
        #pragma unroll
        for (int k4 = 0; k4 < 4; ++k4)
            a1 = __builtin_amdgcn_mfma_f32_16x16x32_bf16(wf[k4], hb[1][k4], a1, 0, 0, 0);
        pl0 += fmaxf(a0[0] + b2v.x, 0.f) * w3v.x + fmaxf(a0[1] + b2v.y, 0.f) * w3v.y
             + fmaxf(a0[2] + b2v.z, 0.f) * w3v.z + fmaxf(a0[3] + b2v.w, 0.f) * w3v.w;
        pl1 += fmaxf(a1[0] + b2v.x, 0.f) * w3v.x + fmaxf(a1[1] + b2v.y, 0.f) * w3v.y
             + fmaxf(a1[2] + b2v.z, 0.f) * w3v.z + fmaxf(a1[3] + b2v.w, 0.f) * w3v.w;
    }
    // reduce over the 4 (l>>4) register-row groups -> full 128-ch dot
    pl0 += __shfl_xor(pl0, 16); pl0 += __shfl_xor(pl0, 32);
    pl1 += __shfl_xor(pl1, 16); pl1 += __shfl_xor(pl1, 32);

    // ---- in-wave softmax over this wave's node (32 edges)
    float mx = fmaxf(pl0, pl1);
    #pragma unroll
    for (int mask = 1; mask <= 8; mask <<= 1) mx = fmaxf(mx, __shfl_xor(mx, mask));
    float e0 = __expf(pl0 - mx), e1 = __expf(pl1 - mx);
    float sm = e0 + e1;
    #pragma unroll
    for (int mask = 1; mask <= 8; mask <<= 1) sm += __shfl_xor(sm, mask);
    if (l < 16) {
        float inv = __frcp_rn(sm);
        s_att[w * DEG + l]      = e0 * inv;
        s_att[w * DEG + 16 + l] = e1 * inv;
    }
    __syncthreads();

    // ---- attention-weighted sum with prefetched rows (exact fp32)
    float4 o = make_float4(0.f, 0.f, 0.f, 0.f);
    #pragma unroll
    for (int j = 0; j < 16; ++j) {
        float a = s_att[g * DEG + jg * 16 + j];
        o.x = fmaf(a, pre[j].x, o.x); o.y = fmaf(a, pre[j].y, o.y);
        o.z = fmaf(a, pre[j].z, o.z); o.w = fmaf(a, pre[j].w, o.w);
    }
    s_part[jg * 128 + unit] = o;
    __syncthreads();
    if (t < 128) {
        float4 r0 = s_part[t], r1 = s_part[128 + t];
        float4 r = make_float4(r0.x + r1.x, r0.y + r1.y, r0.z + r1.z, r0.w + r1.w);
        int gg = t >> 5, cc = t & 31;
        if (base + gg < n) out4[(size_t)(base + gg) * 32 + cc] = r;
    }
}

// ---------------------------------------------------------------------------
extern "C" void kernel_launch(void* const* d_in, const int* in_sizes, int n_in,
                              void* d_out, int out_size, void* d_ws, size_t ws_size,
                              hipStream_t stream)
{
    const int*   nodes = (const int*)  d_in[0];
    const int*   neigh = (const int*)  d_in[1];
    const float* u2e   = (const float*)d_in[3];
    const float* W1    = (const float*)d_in[4];
    const float* b1    = (const float*)d_in[5];
    const float* W2    = (const float*)d_in[6];
    const float* b2    = (const float*)d_in[7];
    const float* w3    = (const float*)d_in[8];
    // d_in[9] b3: cancels in segment softmax

    const int n = in_sizes[0];            // 20000
    const int U = in_sizes[3] / DD;       // 100000

    uint4*  w1img = (uint4*)d_ws;                 // 64 KB (4096 uint4)
    uint4*  w2t   = w1img + 4096;                 // 32 KB (2048 uint4)
    ushort* Pb    = (ushort*)(w2t + 2048);        // 25.6 MB
    ushort* Qb    = Pb + (size_t)U * DD;          // 25.6 MB

    k_prep<<<24, 256, 0, stream>>>(W1, W2, w1img, w2t);
    k_pq<<<(U + 127) / 128, 256, 0, stream>>>(u2e, b1, (const short8*)w1img, Pb, Qb, U);
    k_node<<<(n + 3) / 4, 256, 0, stream>>>(nodes, neigh, (const float4*)u2e,
                                            (const uint4*)Pb, (const uint4*)Qb,
                                            (const short8*)w2t, b2, w3,
                                            (float4*)d_out, n);
}

// Round 5
// 118.597 us; speedup vs baseline: 12.7182x; 1.1178x over previous
//
#include <hip/hip_runtime.h>
#include <hip/hip_bf16.h>

#define DD 128
#define DEG 32

typedef __attribute__((ext_vector_type(8))) short short8;
typedef __attribute__((ext_vector_type(8))) _Float16 half8;
typedef __attribute__((ext_vector_type(4))) float f32x4;

__device__ __forceinline__ ushort f2bs(float x) {
    __hip_bfloat16 h = __float2bfloat16(x);     // RNE
    return *reinterpret_cast<ushort*>(&h);
}
__device__ __forceinline__ float bs2f(ushort u) {
    return __uint_as_float(((unsigned)u) << 16);   // exact widening
}
__device__ __forceinline__ unsigned pack2(float a, float b) {
    return (unsigned)f2bs(a) | ((unsigned)f2bs(b) << 16);
}
// relu(bf16(p_lo)+bf16(q_lo)), relu(bf16(p_hi)+bf16(q_hi)) -> packed bf16 pair
__device__ __forceinline__ unsigned relu_add_pack(unsigned p, unsigned q) {
    float a0 = __uint_as_float(p << 16)        + __uint_as_float(q << 16);
    float a1 = __uint_as_float(p & 0xffff0000u) + __uint_as_float(q & 0xffff0000u);
    return pack2(fmaxf(a0, 0.f), fmaxf(a1, 0.f));
}

// ---------------------------------------------------------------------------
// k_prep: build MFMA fragment images in ws (read straight from global later).
//  w1img (64KB): frag(nt,k4,l)[i] = B1[k4*32+(l>>4)*8+i][nt*16+(l&15)]
//     where B1[k][n] = W1[k][n] (n<128)  |  W1[128+k][n-128] (n>=128)
//  w2t   (32KB): frag(mt,k4,l)[i] = W2[k4*32+(l>>4)*8+i][mt*16+(l&15)]
// (identical lane layout serves as either MFMA A- or B-operand)
// ---------------------------------------------------------------------------
__global__ __launch_bounds__(256) void k_prep(
    const float* __restrict__ W1, const float* __restrict__ W2,
    uint4* __restrict__ w1img, uint4* __restrict__ w2t)
{
    int t = blockIdx.x * 256 + threadIdx.x;
    if (t < 4096) {                     // w1: idx = (nt*4+k4)*64 + l
        int l = t & 63, f = t >> 6, k4 = f & 3, nt = f >> 2;
        int n = nt * 16 + (l & 15), kb = k4 * 32 + ((l >> 4) & 3) * 8;
        float v[8];
        #pragma unroll
        for (int i = 0; i < 8; ++i) {
            int k = kb + i;
            v[i] = (n < DD) ? W1[k * DD + n] : W1[(DD + k) * DD + (n - DD)];
        }
        uint4 r;
        r.x = pack2(v[0], v[1]); r.y = pack2(v[2], v[3]);
        r.z = pack2(v[4], v[5]); r.w = pack2(v[6], v[7]);
        w1img[t] = r;
    } else if (t < 6144) {              // w2t: idx = (mt*4+k4)*64 + l
        int q = t - 4096;
        int l = q & 63, f = q >> 6, k4 = f & 3, mt = f >> 2;
        int ch = mt * 16 + (l & 15), kb = k4 * 32 + ((l >> 4) & 3) * 8;
        float v[8];
        #pragma unroll
        for (int i = 0; i < 8; ++i) v[i] = W2[(kb + i) * DD + ch];
        uint4 r;
        r.x = pack2(v[0], v[1]); r.y = pack2(v[2], v[3]);
        r.z = pack2(v[4], v[5]); r.w = pack2(v[6], v[7]);
        w2t[q] = r;
    }
}

// ---------------------------------------------------------------------------
// k_pq: [P|Q](u) = u2e[u] @ [W1a|W1b] (+b1 on Q), bf16 out; also e16=fp16(u2e).
// 128 users/block. Swapped epilogue: D=mfma(W1frag, u2efrag) -> row=ch,
// col=user -> one 8B store of 4 consecutive channels per lane.
// ---------------------------------------------------------------------------
__global__ __launch_bounds__(256) void k_pq(
    const float* __restrict__ u2e, const float* __restrict__ b1,
    const short8* __restrict__ w1img, ushort* __restrict__ Pb,
    ushort* __restrict__ Qb, _Float16* __restrict__ e16, int U)
{
    __shared__ __align__(16) char a_lds[128 * 256];   // 32 KB bf16 swizzled
    const int t = threadIdx.x;
    const int w = t >> 6, l = t & 63;
    const int base = blockIdx.x * 128;

    #pragma unroll
    for (int i = 0; i < 8; ++i) {
        int flat = i * 256 + t;               // (row, c8) over 128x16
        int row = flat >> 4, c8 = flat & 15;
        int grow = base + row;
        float4 v0 = make_float4(0, 0, 0, 0), v1 = v0;
        if (grow < U) {
            v0 = *reinterpret_cast<const float4*>(&u2e[(size_t)grow * DD + c8 * 8]);
            v1 = *reinterpret_cast<const float4*>(&u2e[(size_t)grow * DD + c8 * 8 + 4]);
        }
        if (grow < U) {                       // fp16 copy for k_node final gather
            half8 hv;
            hv[0] = (_Float16)v0.x; hv[1] = (_Float16)v0.y;
            hv[2] = (_Float16)v0.z; hv[3] = (_Float16)v0.w;
            hv[4] = (_Float16)v1.x; hv[5] = (_Float16)v1.y;
            hv[6] = (_Float16)v1.z; hv[7] = (_Float16)v1.w;
            *reinterpret_cast<half8*>(&e16[(size_t)grow * DD + c8 * 8]) = hv;
        }
        uint4 r;
        r.x = pack2(v0.x, v0.y); r.y = pack2(v0.z, v0.w);
        r.z = pack2(v1.x, v1.y); r.w = pack2(v1.z, v1.w);
        int off = (row * 256 + c8 * 16) ^ ((row & 7) << 4);
        *reinterpret_cast<uint4*>(a_lds + off) = r;
    }
    __syncthreads();

    short8 a[2][4];       // this wave's 2 user-tiles (B-operand role)
    #pragma unroll
    for (int mt = 0; mt < 2; ++mt) {
        int row = w * 32 + mt * 16 + (l & 15);
        int sw = (row & 7) << 4;
        #pragma unroll
        for (int k4 = 0; k4 < 4; ++k4)
            a[mt][k4] = *reinterpret_cast<const short8*>(
                a_lds + ((row * 256 + k4 * 64 + (l >> 4) * 16) ^ sw));
    }

    const int chq = (l >> 4) << 2;            // lane's 4-channel sub-block
    // ---- P half: output channels 0..127
    #pragma unroll 2
    for (int mt = 0; mt < 8; ++mt) {
        short8 wf[4];
        #pragma unroll
        for (int k4 = 0; k4 < 4; ++k4) wf[k4] = w1img[(mt * 4 + k4) * 64 + l];
        #pragma unroll
        for (int ntu = 0; ntu < 2; ++ntu) {
            f32x4 acc = {0.f, 0.f, 0.f, 0.f};
            #pragma unroll
            for (int k4 = 0; k4 < 4; ++k4)
                acc = __builtin_amdgcn_mfma_f32_16x16x32_bf16(wf[k4], a[ntu][k4], acc, 0, 0, 0);
            int user = base + w * 32 + ntu * 16 + (l & 15);
            if (user < U) {
                uint2 pk;
                pk.x = pack2(acc[0], acc[1]); pk.y = pack2(acc[2], acc[3]);
                *reinterpret_cast<uint2*>(&Pb[(size_t)user * DD + mt * 16 + chq]) = pk;
            }
        }
    }
    // ---- Q half: output channels 128..255, fold b1
    #pragma unroll 2
    for (int mt = 8; mt < 16; ++mt) {
        short8 wf[4];
        #pragma unroll
        for (int k4 = 0; k4 < 4; ++k4) wf[k4] = w1img[(mt * 4 + k4) * 64 + l];
        float4 b1v = *reinterpret_cast<const float4*>(&b1[(mt - 8) * 16 + chq]);
        #pragma unroll
        for (int ntu = 0; ntu < 2; ++ntu) {
            f32x4 acc = {0.f, 0.f, 0.f, 0.f};
            #pragma unroll
            for (int k4 = 0; k4 < 4; ++k4)
                acc = __builtin_amdgcn_mfma_f32_16x16x32_bf16(wf[k4], a[ntu][k4], acc, 0, 0, 0);
            int user = base + w * 32 + ntu * 16 + (l & 15);
            if (user < U) {
                uint2 pk;
                pk.x = pack2(acc[0] + b1v.x, acc[1] + b1v.y);
                pk.y = pack2(acc[2] + b1v.z, acc[3] + b1v.w);
                *reinterpret_cast<uint2*>(&Qb[(size_t)user * DD + (mt - 8) * 16 + chq]) = pk;
            }
        }
    }
}

// ---------------------------------------------------------------------------
// k_node: 4 nodes/block (1 node per wave for the GEMM).
//  pre-gather e16 rows (fp16) first for max MLP; h1 = relu(P[nb]+Q[u]) ->
//  bf16 swizzled LDS; swapped GEMM D[ch][edge]; in-lane logit + 2 shuffles;
//  in-wave softmax; fp32 weighted sum from fp16 prefetch.
// ---------------------------------------------------------------------------
__global__ __launch_bounds__(256) void k_node(
    const int* __restrict__ nodes, const int* __restrict__ neigh,
    const _Float16* __restrict__ e16, const uint4* __restrict__ Pb4,
    const uint4* __restrict__ Qb4, const short8* __restrict__ w2t,
    const float* __restrict__ b2, const float* __restrict__ w3,
    float4* __restrict__ out4, int n)
{
    __shared__ __align__(16) char h_lds[128 * 256];   // 32 KB; aliased post-GEMM
    __shared__ uint4 s_q16[4][16];                    // Q rows, packed bf16
    __shared__ int   s_nb[128];
    __shared__ int   s_u[4];
    __shared__ float s_att[128];
    float* s_partf = reinterpret_cast<float*>(h_lds); // [4][4][128] floats (8 KB)

    const int t = threadIdx.x;
    const int w = t >> 6, l = t & 63;
    const int base = blockIdx.x * 4;

    if (t < 4)   s_u[t] = nodes[min(base + t, n - 1)];
    if (t < 128) s_nb[t] = neigh[min(base * DEG + t, n * DEG - 1)];
    __syncthreads();
    if (t < 64)  s_q16[t >> 4][t & 15] = Qb4[(size_t)s_u[t >> 4] * 16 + (t & 15)];
    __syncthreads();

    // ---- prefetch e16 rows FIRST (deep MLP: 8 pre + 8 Pb loads in flight)
    // 256 threads = (jg = wave) x (g4 node) x (c8 8-col chunk); 8 edges each.
    const int g4 = (t >> 4) & 3, c8 = t & 15, jg = t >> 6;
    half8 pre[8];
    #pragma unroll
    for (int j = 0; j < 8; ++j)
        pre[j] = *reinterpret_cast<const half8*>(
            &e16[(size_t)s_nb[g4 * DEG + jg * 8 + j] * DD + c8 * 8]);

    // ---- h1 build: gather Pb rows, add Q, relu, store swizzled bf16
    #pragma unroll
    for (int i = 0; i < 8; ++i) {
        int flat = i * 256 + t;               // (row, c8) over 128x16
        int row = flat >> 4, cc = flat & 15;
        int nb = s_nb[row];
        uint4 pv = Pb4[(size_t)nb * 16 + cc];
        uint4 qv = s_q16[row >> 5][cc];
        uint4 r;
        r.x = relu_add_pack(pv.x, qv.x);
        r.y = relu_add_pack(pv.y, qv.y);
        r.z = relu_add_pack(pv.z, qv.z);
        r.w = relu_add_pack(pv.w, qv.w);
        int off = (row * 256 + cc * 16) ^ ((row & 7) << 4);
        *reinterpret_cast<uint4*>(h_lds + off) = r;
    }
    __syncthreads();

    // ---- swapped GEMM + logit fold (wave w = node w, 32 edges)
    short8 hb[2][4];
    #pragma unroll
    for (int nt = 0; nt < 2; ++nt) {
        int erow = w * 32 + nt * 16 + (l & 15);
        int sw = (erow & 7) << 4;
        #pragma unroll
        for (int k4 = 0; k4 < 4; ++k4)
            hb[nt][k4] = *reinterpret_cast<const short8*>(
                h_lds + ((erow * 256 + k4 * 64 + (l >> 4) * 16) ^ sw));
    }
    float pl0 = 0.f, pl1 = 0.f;
    #pragma unroll
    for (int mt = 0; mt < 8; ++mt) {
        short8 wf[4];
        #pragma unroll
        for (int k4 = 0; k4 < 4; ++k4) wf[k4] = w2t[(mt * 4 + k4) * 64 + l];
        float4 b2v = *reinterpret_cast<const float4*>(&b2[mt * 16 + (l >> 4) * 4]);
        float4 w3v = *reinterpret_cast<const float4*>(&w3[mt * 16 + (l >> 4) * 4]);
        f32x4 a0 = {0.f, 0.f, 0.f, 0.f}, a1 = {0.f, 0.f, 0.f, 0.f};
        #pragma unroll
        for (int k4 = 0; k4 < 4; ++k4)
            a0 = __builtin_amdgcn_mfma_f32_16x16x32_bf16(wf[k4], hb[0][k4], a0, 0, 0, 0);
        #pragma unroll
        for (int k4 = 0; k4 < 4; ++k4)
            a1 = __builtin_amdgcn_mfma_f32_16x16x32_bf16(wf[k4], hb[1][k4], a1, 0, 0, 0);
        pl0 += fmaxf(a0[0] + b2v.x, 0.f) * w3v.x + fmaxf(a0[1] + b2v.y, 0.f) * w3v.y
             + fmaxf(a0[2] + b2v.z, 0.f) * w3v.z + fmaxf(a0[3] + b2v.w, 0.f) * w3v.w;
        pl1 += fmaxf(a1[0] + b2v.x, 0.f) * w3v.x + fmaxf(a1[1] + b2v.y, 0.f) * w3v.y
             + fmaxf(a1[2] + b2v.z, 0.f) * w3v.z + fmaxf(a1[3] + b2v.w, 0.f) * w3v.w;
    }
    pl0 += __shfl_xor(pl0, 16); pl0 += __shfl_xor(pl0, 32);
    pl1 += __shfl_xor(pl1, 16); pl1 += __shfl_xor(pl1, 32);

    // ---- in-wave softmax over this wave's node (32 edges)
    float mx = fmaxf(pl0, pl1);
    #pragma unroll
    for (int mask = 1; mask <= 8; mask <<= 1) mx = fmaxf(mx, __shfl_xor(mx, mask));
    float e0 = __expf(pl0 - mx), e1 = __expf(pl1 - mx);
    float sm = e0 + e1;
    #pragma unroll
    for (int mask = 1; mask <= 8; mask <<= 1) sm += __shfl_xor(sm, mask);
    if (l < 16) {
        float inv = __frcp_rn(sm);
        s_att[w * DEG + l]      = e0 * inv;
        s_att[w * DEG + 16 + l] = e1 * inv;
    }
    __syncthreads();   // also: all waves done reading h_lds -> safe to alias

    // ---- attention-weighted sum from fp16 prefetch (exact fp32 accum)
    float o[8] = {0.f, 0.f, 0.f, 0.f, 0.f, 0.f, 0.f, 0.f};
    #pragma unroll
    for (int j = 0; j < 8; ++j) {
        float a = s_att[g4 * DEG + jg * 8 + j];
        #pragma unroll
        for (int i = 0; i < 8; ++i)
            o[i] = fmaf(a, (float)pre[j][i], o[i]);
    }
    {
        float* sp = s_partf + ((jg * 4 + g4) * 128 + c8 * 8);
        #pragma unroll
        for (int i = 0; i < 8; ++i) sp[i] = o[i];
    }
    __syncthreads();
    if (t < 128) {
        int g = t >> 5, c4 = t & 31;
        float4 r = make_float4(0.f, 0.f, 0.f, 0.f);
        #pragma unroll
        for (int j2 = 0; j2 < 4; ++j2) {
            const float* sp = s_partf + ((j2 * 4 + g) * 128 + c4 * 4);
            r.x += sp[0]; r.y += sp[1]; r.z += sp[2]; r.w += sp[3];
        }
        if (base + g < n) out4[(size_t)(base + g) * 32 + c4] = r;
    }
}

// ---------------------------------------------------------------------------
extern "C" void kernel_launch(void* const* d_in, const int* in_sizes, int n_in,
                              void* d_out, int out_size, void* d_ws, size_t ws_size,
                              hipStream_t stream)
{
    const int*   nodes = (const int*)  d_in[0];
    const int*   neigh = (const int*)  d_in[1];
    const float* u2e   = (const float*)d_in[3];
    const float* W1    = (const float*)d_in[4];
    const float* b1    = (const float*)d_in[5];
    const float* W2    = (const float*)d_in[6];
    const float* b2    = (const float*)d_in[7];
    const float* w3    = (const float*)d_in[8];
    // d_in[9] b3: cancels in segment softmax

    const int n = in_sizes[0];            // 20000
    const int U = in_sizes[3] / DD;       // 100000

    uint4*     w1img = (uint4*)d_ws;                  // 64 KB (4096 uint4)
    uint4*     w2t   = w1img + 4096;                  // 32 KB (2048 uint4)
    ushort*    Pb    = (ushort*)(w2t + 2048);         // 25.6 MB
    ushort*    Qb    = Pb + (size_t)U * DD;           // 25.6 MB
    _Float16*  e16   = (_Float16*)(Qb + (size_t)U * DD); // 25.6 MB

    k_prep<<<24, 256, 0, stream>>>(W1, W2, w1img, w2t);
    k_pq<<<(U + 127) / 128, 256, 0, stream>>>(u2e, b1, (const short8*)w1img,
                                              Pb, Qb, e16, U);
    k_node<<<(n + 3) / 4, 256, 0, stream>>>(nodes, neigh, e16,
                                            (const uint4*)Pb, (const uint4*)Qb,
                                            (const short8*)w2t, b2, w3,
                                            (float4*)d_out, n);
}